// Round 7
// baseline (201.542 us; speedup 1.0000x reference)
//
#include <hip/hip_runtime.h>

// EquiConv fused MFMA kernel for MI355X (gfx950) — round 7.
// R6 post-mortem: 56% stall (ring WAITV6/WAITL0 chain) + VALU-dominated busy
// (A-frag packs). Two structural fixes:
//  1) mfma_f32_32x32x16_bf16: M=32 edges/tile -> per-lane A-pack feeds 2x the
//     MACs (A-gen VALU halves), MFMA count halves. C/D layout per m74/m101.
//  2) B-path: global->VGPR direct (1KB frag = 16B/lane coalesced dwordx4).
//     LDS ring + manual waitcnt protocol deleted (R4/R5 bug class gone);
//     compiler auto-schedules loads with fine-grained vmcnt.
// K-split-4 kept: wave wv owns u-quarter; cross-wave reduce via 12 LDS slots;
// waves 0/1 run FC + epilogue (w0: sc cols, w1: vec cols). Grid 625 x 256thr.

#define E_TOT 20000

typedef __attribute__((ext_vector_type(8))) short short8;
typedef __attribute__((ext_vector_type(4))) float f32x4;
typedef __attribute__((ext_vector_type(16))) float f32x16;
typedef __attribute__((ext_vector_type(2))) __bf16 bf16x2;

#define FRAG_USH 512
#define NFRAG_W  304                     // frags per wave stream (no pads)
#define STRIDE_W (NFRAG_W*FRAG_USH)      // 155648 ushort
#define FC1_OFF  (4*STRIDE_W)            // 622592
#define FC2_OFF  (FC1_OFF+8192)          // 630784
#define FC3_OFF  (FC2_OFF+4096)          // 634880
#define WS_USH   (FC3_OFF+6144)          // 641024 ushort = 1.25 MB

// src cumulative offsets (prep thread = one src element)
#define O_SSG 262144
#define O_VVS (O_SSG+131072)   // 393216
#define O_VVG (O_VVS+65536)    // 458752
#define O_SV  (O_VVG+32768)    // 491520
#define O_VS  (O_SV+65536)     // 557056
#define O_F1  (O_VS+65536)     // 622592
#define O_F2  (O_F1+8192)      // 630784
#define O_F3  (O_F2+4096)      // 634880
#define N_SRC (O_F3+6144)      // 641024

__device__ __forceinline__ unsigned short f2b(float f){
  return __builtin_bit_cast(unsigned short, (__bf16)f);
}
__device__ __forceinline__ unsigned f2b2(float lo, float hi){
  bf16x2 t; t[0] = (__bf16)lo; t[1] = (__bf16)hi;
  return __builtin_bit_cast(unsigned, t);
}
__device__ __forceinline__ float b2f(unsigned short h){
  return __uint_as_float(((unsigned)h) << 16);
}
__device__ __forceinline__ f32x16 mfma32(short8 a, short8 b, f32x16 c){
  return __builtin_amdgcn_mfma_f32_32x32x16_bf16(a, b, c, 0, 0, 0);
}
union U8 { short8 v; unsigned u[4]; };
__device__ __forceinline__ float silu_f(float x){ return x/(1.f+__expf(-x)); }
__device__ __forceinline__ float sigm_f(float x){ return 1.f/(1.f+__expf(-x)); }

#define PACK8(a, s, x) \
  a.u[0]=f2b2((s)*(x)[0],(s)*(x)[1]); a.u[1]=f2b2((s)*(x)[2],(s)*(x)[3]); \
  a.u[2]=f2b2((s)*(x)[4],(s)*(x)[5]); a.u[3]=f2b2((s)*(x)[6],(s)*(x)[7]);

#define Z16(T) { _Pragma("unroll") for (int k_=0;k_<16;k_++) (T)[k_]=0.f; }

// position of (k_local in [0,16), n in [0,32)) inside a 512-ushort B frag:
// lane = (k>>3)*32 + n, j = k&7  (B layout: n=lane&31, k=(lane>>5)*8+j)
__device__ __forceinline__ int fpos32(int kl, int n){
  return ((kl>>3)*32 + n)*8 + (kl&7);
}

// ---------------- prep: src-linear scatter into per-wave frag streams ----------------
// Wave stream (frag-linear): SS frags 0..191 (ul*12+q*3+t; q=v>>4, t: 0,1=sc
// w-halves, 2=g), VV 192..239 (ul*6+q*3+t), SV 240..271 (ul*2+q), VS 272..303
// (ul*4+q). FC frags appended after the 4 streams.
__global__ void prep_weights(const float* __restrict__ ss_s, const float* __restrict__ ss_g,
                             const float* __restrict__ vv_s, const float* __restrict__ vv_g,
                             const float* __restrict__ sv,   const float* __restrict__ vs,
                             const float* __restrict__ w1,   const float* __restrict__ w2,
                             const float* __restrict__ w3,   unsigned short* __restrict__ wsb)
{
  int idx = blockIdx.x * 256 + threadIdx.x;
  if (idx >= N_SRC) return;
  const float A_SC  = 0.013975424859373686f;                     // 1/sqrt(S*S+V*V)
  const float A_VV  = (float)(0.013975424859373686 * 0.5773502691896258);
  const float A_VEC = 0.015625f;                                 // 1/sqrt(2*S*V)
  float val; int dest;
  if (idx < O_SSG){                         // ss_s [64][64][64]
    int i = idx;
    int u = i >> 12, v = (i >> 6) & 63, w = i & 63;
    int wave = u >> 4, ul = u & 15;
    int frag = ul*12 + (v>>4)*3 + (w>>5);
    dest = wave*STRIDE_W + frag*FRAG_USH + fpos32(v&15, w&31);
    val = A_SC * ss_s[i];
  } else if (idx < O_VVS){                  // ss_g [64][64][32] -> t=2
    int i = idx - O_SSG;
    int u = i >> 11, v = (i >> 5) & 63, w = i & 31;
    int wave = u >> 4, ul = u & 15;
    int frag = ul*12 + (v>>4)*3 + 2;
    dest = wave*STRIDE_W + frag*FRAG_USH + fpos32(v&15, w);
    val = A_SC * ss_g[i];
  } else if (idx < O_VVG){                  // vv_s [32][32][64]
    int i = idx - O_VVS;
    int u = i >> 11, v = (i >> 6) & 31, w = i & 63;
    int wave = u >> 3, ul = u & 7;
    int frag = 192 + ul*6 + (v>>4)*3 + (w>>5);
    dest = wave*STRIDE_W + frag*FRAG_USH + fpos32(v&15, w&31);
    val = A_VV * vv_s[i];
  } else if (idx < O_SV){                   // vv_g [32][32][32] -> t=2
    int i = idx - O_VVG;
    int u = i >> 10, v = (i >> 5) & 31, w = i & 31;
    int wave = u >> 3, ul = u & 7;
    int frag = 192 + ul*6 + (v>>4)*3 + 2;
    dest = wave*STRIDE_W + frag*FRAG_USH + fpos32(v&15, w);
    val = A_VV * vv_g[i];
  } else if (idx < O_VS){                   // sv [64][32][32]
    int i = idx - O_SV;
    int u = i >> 10, v = (i >> 5) & 31, w = i & 31;
    int wave = u >> 4, ul = u & 15;
    int frag = 240 + ul*2 + (v>>4);
    dest = wave*STRIDE_W + frag*FRAG_USH + fpos32(v&15, w);
    val = A_VEC * sv[i];
  } else if (idx < O_F1){                   // vs [32][64][32]
    int i = idx - O_VS;
    int u = i >> 11, v = (i >> 5) & 63, w = i & 31;
    int wave = u >> 3, ul = u & 7;
    int frag = 272 + ul*4 + (v>>4);
    dest = wave*STRIDE_W + frag*FRAG_USH + fpos32(v&15, w);
    val = A_VEC * vs[i];
  } else if (idx < O_F2){                   // fc1 [128][64]
    int i = idx - O_F1;
    int k = i >> 6, n = i & 63;
    dest = FC1_OFF + ((k>>4)*2 + (n>>5))*FRAG_USH + fpos32(k&15, n&31);
    val = w1[i];
  } else if (idx < O_F3){                   // fc2 [64][64]
    int i = idx - O_F2;
    int k = i >> 6, n = i & 63;
    dest = FC2_OFF + ((k>>4)*2 + (n>>5))*FRAG_USH + fpos32(k&15, n&31);
    val = w2[i];
  } else {                                  // fc3 [64][96]
    int i = idx - O_F3;
    int k = i / 96, n = i - k*96;
    dest = FC3_OFF + ((k>>4)*3 + (n>>5))*FRAG_USH + fpos32(k&15, n&31);
    val = w3[i];
  }
  wsb[dest] = f2b(val);
}

// ---------------- main fused kernel ----------------
__global__ __launch_bounds__(256, 2)
void equiconv_main(const float* __restrict__ fea1,
                   const float* __restrict__ fea2,
                   const float* __restrict__ few,
                   const float* __restrict__ fb1,
                   const float* __restrict__ fb2,
                   const float* __restrict__ fb3,
                   const unsigned short* __restrict__ wsb,
                   float* __restrict__ out)
{
  __shared__ __align__(16) unsigned short x1s[32][66];
  __shared__ __align__(16) unsigned short x1v[32][98];
  __shared__ __align__(16) unsigned short hb[2][32][72];   // wave-private FC h buf
  __shared__ __align__(16) float redf[12*1024];            // 12 tile slots, 48 KB

  const int tid  = threadIdx.x;
  const int lane = tid & 63, wv = tid >> 6;
  const int n    = lane & 31;            // MFMA col / this lane's edge row (m)
  const int kh   = lane >> 5;            // k-half select
  const int ko   = kh << 3;              // k offset within 16-chunk
  const int ebase = blockIdx.x << 5;     // 625 * 32 == 20000 exactly

  // ---- stage x1 (32 edges) into LDS as bf16 ----
  for (int it = tid; it < 1280; it += 256){
    int row = it / 40, seg = it - row*40;
    float4 v1 = *(const float4*)(fea1 + (size_t)(ebase + row)*160 + seg*4);
    const float* p1 = (const float*)&v1;
    int c0 = seg*4;
    #pragma unroll
    for (int jj = 0; jj < 4; jj++){
      int col = c0 + jj;
      if (col < 64) x1s[row][col] = f2b(p1[jj]);
      else          x1v[row][col-64] = f2b(p1[jj]);
    }
  }
  __syncthreads();

  // ---- hoist per-lane x2 slices (A-layout: m=lane&31, k=(lane>>5)*8+j) ----
  float xq[4][8];         // x2s[e][q*16+ko+j]
  float yv[3][2][8];      // x2v[e][q*16+ko+j][i]
  {
    const float* p = fea2 + (size_t)(ebase + n)*160;
    #pragma unroll
    for (int q = 0; q < 4; q++){
      float4 a0 = *(const float4*)(p + q*16 + ko);
      float4 a1 = *(const float4*)(p + q*16 + ko + 4);
      xq[q][0]=a0.x; xq[q][1]=a0.y; xq[q][2]=a0.z; xq[q][3]=a0.w;
      xq[q][4]=a1.x; xq[q][5]=a1.y; xq[q][6]=a1.z; xq[q][7]=a1.w;
    }
    #pragma unroll
    for (int q = 0; q < 2; q++){
      float yb[24];
      const float* py = p + 64 + (q*16 + ko)*3;
      #pragma unroll
      for (int t = 0; t < 6; t++){
        float4 f4 = *(const float4*)(py + 4*t);
        yb[4*t]=f4.x; yb[4*t+1]=f4.y; yb[4*t+2]=f4.z; yb[4*t+3]=f4.w;
      }
      #pragma unroll
      for (int j = 0; j < 8; j++){
        yv[0][q][j] = yb[3*j]; yv[1][q][j] = yb[3*j+1]; yv[2][q][j] = yb[3*j+2];
      }
    }
  }

  f32x16 T[6];                 // 0,1: sc w-halves; 2: g; 3,4,5: vec comps
  #pragma unroll
  for (int j = 0; j < 6; j++) Z16(T[j]);

  const short8* G = (const short8*)(wsb + (size_t)wv*STRIDE_W);

  // ===== SS: frags 0..191 =====
  #pragma unroll 2
  for (int ul = 0; ul < 16; ul++){
    float s = b2f(x1s[n][(wv<<4) + ul]);
    #pragma unroll
    for (int q = 0; q < 4; q++){
      U8 a; PACK8(a, s, xq[q]);
      #pragma unroll
      for (int t = 0; t < 3; t++)
        T[t] = mfma32(a.v, G[(ul*12 + q*3 + t)*64 + lane], T[t]);
    }
  }
  // ===== VV: frags 192..239 =====
  #pragma unroll 2
  for (int ul = 0; ul < 8; ul++){
    int u = (wv<<3) + ul;
    float c0 = b2f(x1v[n][u*3+0]);
    float c1 = b2f(x1v[n][u*3+1]);
    float c2 = b2f(x1v[n][u*3+2]);
    #pragma unroll
    for (int q = 0; q < 2; q++){
      float pv[8];
      #pragma unroll
      for (int j = 0; j < 8; j++)
        pv[j] = c0*yv[0][q][j] + c1*yv[1][q][j] + c2*yv[2][q][j];
      U8 a;
      a.u[0]=f2b2(pv[0],pv[1]); a.u[1]=f2b2(pv[2],pv[3]);
      a.u[2]=f2b2(pv[4],pv[5]); a.u[3]=f2b2(pv[6],pv[7]);
      #pragma unroll
      for (int t = 0; t < 3; t++)
        T[t] = mfma32(a.v, G[(192 + ul*6 + q*3 + t)*64 + lane], T[t]);
    }
  }
  // ===== SV: frags 240..271 =====
  #pragma unroll 2
  for (int ul = 0; ul < 16; ul++){
    float s = b2f(x1s[n][(wv<<4) + ul]);
    #pragma unroll
    for (int q = 0; q < 2; q++){
      short8 b = G[(240 + ul*2 + q)*64 + lane];
      U8 a0, a1, a2;
      PACK8(a0, s, yv[0][q]); PACK8(a1, s, yv[1][q]); PACK8(a2, s, yv[2][q]);
      T[3] = mfma32(a0.v, b, T[3]);
      T[4] = mfma32(a1.v, b, T[4]);
      T[5] = mfma32(a2.v, b, T[5]);
    }
  }
  // ===== VS: frags 272..303 =====
  #pragma unroll 2
  for (int ul = 0; ul < 8; ul++){
    int u = (wv<<3) + ul;
    float c0 = b2f(x1v[n][u*3+0]);
    float c1 = b2f(x1v[n][u*3+1]);
    float c2 = b2f(x1v[n][u*3+2]);
    #pragma unroll
    for (int q = 0; q < 4; q++){
      short8 b = G[(272 + ul*4 + q)*64 + lane];
      U8 a0, a1, a2;
      PACK8(a0, c0, xq[q]); PACK8(a1, c1, xq[q]); PACK8(a2, c2, xq[q]);
      T[3] = mfma32(a0.v, b, T[3]);
      T[4] = mfma32(a1.v, b, T[4]);
      T[5] = mfma32(a2.v, b, T[5]);
    }
  }

  // ---- cross-wave K-reduction: 12 slots x 4KB; final: w0 owns T0,T1; w1 owns T2..T5 ----
  #define PUTT(slot, Tt) { _Pragma("unroll") for (int k=0;k<4;k++){ \
      f32x4 v_ = { (Tt)[4*k], (Tt)[4*k+1], (Tt)[4*k+2], (Tt)[4*k+3] }; \
      *(f32x4*)(redf + (slot)*1024 + lane*16 + k*4) = v_; } }
  #define ADDT(slot, Tt) { _Pragma("unroll") for (int k=0;k<4;k++){ \
      f32x4 v_ = *(const f32x4*)(redf + (slot)*1024 + lane*16 + k*4); \
      (Tt)[4*k]+=v_[0]; (Tt)[4*k+1]+=v_[1]; (Tt)[4*k+2]+=v_[2]; (Tt)[4*k+3]+=v_[3]; } }

  if (wv == 2){ PUTT(0,T[0]); PUTT(1,T[1]); PUTT(2,T[2]); PUTT(3,T[3]); PUTT(4,T[4]); PUTT(5,T[5]); }
  if (wv == 3){ PUTT(6,T[0]); PUTT(7,T[1]); PUTT(8,T[2]); PUTT(9,T[3]); PUTT(10,T[4]); PUTT(11,T[5]); }
  __syncthreads();
  if (wv == 0){ ADDT(0,T[0]); ADDT(1,T[1]); ADDT(2,T[2]); ADDT(3,T[3]); ADDT(4,T[4]); ADDT(5,T[5]); }
  if (wv == 1){ ADDT(6,T[0]); ADDT(7,T[1]); ADDT(8,T[2]); ADDT(9,T[3]); ADDT(10,T[4]); ADDT(11,T[5]); }
  __syncthreads();
  if (wv == 1){ PUTT(0,T[0]); PUTT(1,T[1]); }
  if (wv == 0){ PUTT(2,T[2]); PUTT(3,T[3]); PUTT(4,T[4]); PUTT(5,T[5]); }
  __syncthreads();
  if (wv == 0){ ADDT(0,T[0]); ADDT(1,T[1]); }
  if (wv == 1){ ADDT(2,T[2]); ADDT(3,T[3]); ADDT(4,T[4]); ADDT(5,T[5]); }

  if (wv >= 2) return;

  // ---- FC chain (w0 and w1 both compute; w0 uses w[:,0:64], w1 uses w[:,64:96]) ----
  f32x16 F0, F1;
  Z16(F0); Z16(F1);
  {
    const float* fp = few + (size_t)(ebase + n)*128;
    const short8* B1 = (const short8*)(wsb + FC1_OFF);
    #pragma unroll
    for (int kc = 0; kc < 8; kc++){
      float4 fa  = *(const float4*)(fp + kc*16 + ko);
      float4 fbv = *(const float4*)(fp + kc*16 + ko + 4);
      U8 a;
      a.u[0]=f2b2(fa.x,fa.y);   a.u[1]=f2b2(fa.z,fa.w);
      a.u[2]=f2b2(fbv.x,fbv.y); a.u[3]=f2b2(fbv.z,fbv.w);
      F0 = mfma32(a.v, B1[(kc*2+0)*64 + lane], F0);
      F1 = mfma32(a.v, B1[(kc*2+1)*64 + lane], F1);
    }
  }
  #pragma unroll
  for (int t = 0; t < 2; t++){
    float bb = fb1[t*32 + n];
    const f32x16& F = t ? F1 : F0;
    #pragma unroll
    for (int r = 0; r < 16; r++){
      int row = (r&3) + 8*(r>>2) + 4*kh;       // C-layout row (m74/m101)
      hb[wv][row][t*32 + n] = f2b(silu_f(F[r] + bb));
    }
  }
  Z16(F0); Z16(F1);
  {
    const short8* B2 = (const short8*)(wsb + FC2_OFF);
    #pragma unroll
    for (int kc = 0; kc < 4; kc++){
      uint4 hq = *(const uint4*)&hb[wv][n][kc*16 + ko];
      U8 a; a.u[0]=hq.x; a.u[1]=hq.y; a.u[2]=hq.z; a.u[3]=hq.w;
      F0 = mfma32(a.v, B2[(kc*2+0)*64 + lane], F0);
      F1 = mfma32(a.v, B2[(kc*2+1)*64 + lane], F1);
    }
  }
  #pragma unroll
  for (int t = 0; t < 2; t++){
    float bb = fb2[t*32 + n];
    const f32x16& F = t ? F1 : F0;
    #pragma unroll
    for (int r = 0; r < 16; r++){
      int row = (r&3) + 8*(r>>2) + 4*kh;
      hb[wv][row][t*32 + n] = f2b(silu_f(F[r] + bb));
    }
  }
  f32x16 W0, W1, W2;
  Z16(W0); Z16(W1); Z16(W2);
  {
    const short8* B3 = (const short8*)(wsb + FC3_OFF);
    #pragma unroll
    for (int kc = 0; kc < 4; kc++){
      uint4 hq = *(const uint4*)&hb[wv][n][kc*16 + ko];
      U8 a; a.u[0]=hq.x; a.u[1]=hq.y; a.u[2]=hq.z; a.u[3]=hq.w;
      W0 = mfma32(a.v, B3[(kc*3+0)*64 + lane], W0);
      W1 = mfma32(a.v, B3[(kc*3+1)*64 + lane], W1);
      W2 = mfma32(a.v, B3[(kc*3+2)*64 + lane], W2);
    }
  }

  // ---- epilogue (C-layout: col=lane&31, row=(r&3)+8*(r>>2)+4*(lane>>5)) ----
  if (wv == 0){
    #pragma unroll
    for (int r = 0; r < 16; r++){
      int row = (r&3) + 8*(r>>2) + 4*kh;
      float* op = out + (size_t)(ebase + row)*160;
      float w0v = W0[r] + fb3[n];
      float w1v = W1[r] + fb3[32 + n];
      op[n]      = silu_f(T[0][r]) * w0v;
      op[32 + n] = silu_f(T[1][r]) * w1v;
    }
  } else {
    #pragma unroll
    for (int r = 0; r < 16; r++){
      int row = (r&3) + 8*(r>>2) + 4*kh;
      float* op = out + (size_t)(ebase + row)*160;
      float wv3 = W2[r] + fb3[64 + n];
      float f = sigm_f(T[2][r]) * wv3;
      op[64 + n*3 + 0] = T[3][r] * f;
      op[64 + n*3 + 1] = T[4][r] * f;
      op[64 + n*3 + 2] = T[5][r] * f;
    }
  }
}

extern "C" void kernel_launch(void* const* d_in, const int* in_sizes, int n_in,
                              void* d_out, int out_size, void* d_ws, size_t ws_size,
                              hipStream_t stream) {
  (void)in_sizes; (void)n_in; (void)out_size; (void)ws_size;
  unsigned short* wsb = (unsigned short*)d_ws;

  prep_weights<<<(N_SRC + 255)/256, 256, 0, stream>>>(
      (const float*)d_in[3], (const float*)d_in[5],     // ss_s, ss_g
      (const float*)d_in[4], (const float*)d_in[6],     // vv_s, vv_g
      (const float*)d_in[7], (const float*)d_in[8],     // sv, vs
      (const float*)d_in[9], (const float*)d_in[11], (const float*)d_in[13],
      wsb);

  equiconv_main<<<E_TOT/32, 256, 0, stream>>>(
      (const float*)d_in[0], (const float*)d_in[1], (const float*)d_in[2],
      (const float*)d_in[10], (const float*)d_in[12], (const float*)d_in[14],
      (const unsigned short*)wsb, (float*)d_out);
}